// Round 13
// baseline (184.037 us; speedup 1.0000x reference)
//
#include <hip/hip_runtime.h>
#include <stdint.h>

#define B_ROWS 16384
#define C_CLS  2000
#define C_PAD  2048
#define F_DIM  1024
#define KT     16                         // K-tiles of 64
#define NRB    64                         // gemm row blocks (256 rows)
#define NCBP   16                         // gemm col panels (128 cols)
#define PANEL_A 262144                    // 16 kt x 16 frags x 1024 B
#define PANEL_BB 131072                   // 16 kt x 8 frags x 1024 B

typedef float f32x4 __attribute__((ext_vector_type(4)));
typedef long long i64x2 __attribute__((ext_vector_type(2)));

#define SCALE_F 4.0f
#define SCALE_W 16.0f
#define INV_SCALE 0.015625f               // 1/64

__device__ __forceinline__ void gl_lds16(const void* g, void* l) {
    __builtin_amdgcn_global_load_lds(
        (const __attribute__((address_space(1))) unsigned int*)g,
        (__attribute__((address_space(3))) unsigned int*)l, 16, 0, 0);
}

__device__ __forceinline__ unsigned int pk4(float a, float b, float c, float d) {
    int u = __builtin_amdgcn_cvt_pk_fp8_f32(a, b, 0, false);   // bytes 0,1
    u = __builtin_amdgcn_cvt_pk_fp8_f32(c, d, u, true);        // bytes 2,3
    return (unsigned int)u;
}

// Fragment-linear panels: frag f covers rows f*16..+16; lane l at byte l*16 of the
// 1024B frag; 16B = k[lhi*8..+8) ∪ [32+lhi*8..+8) (i64x2 = [kf0,kf1]) — R10/R11-verified.

// ---- fused prepass: blocks 0..511 = A (feat->fp8 + fisher), 512..639 = B (W->fp8 + bias) ----
__global__ __launch_bounds__(256)
void prep_kernel(const float* __restrict__ feat, const int* __restrict__ labels,
                 const float* __restrict__ centers, const float* __restrict__ W,
                 const float* __restrict__ bias,
                 char* __restrict__ A_pre, char* __restrict__ B_pre,
                 float* __restrict__ bias_pad, float* __restrict__ fisher_part)
{
    const int tid = threadIdx.x;
    if (blockIdx.x < 512) {
        const int rt = blockIdx.x >> 2, g = blockIdx.x & 3;   // rt: 128-row half-panels
        const int rb = rt >> 1;
        const int r = tid >> 1, h = tid & 1;
        const int grow = rt * 128 + r;
        const int lab = labels[grow];
        const float* frow = feat    + (size_t)grow * F_DIM;
        const float* crow = centers + (size_t)lab  * F_DIM;
        const int frag = (rt & 1) * 8 + (r >> 4);
        char* pan = A_pre + (size_t)rb * PANEL_A + frag * 1024 + (r & 15) * 16;
        float facc = 0.f;
        #pragma unroll
        for (int q = 0; q < 4; ++q) {
            const int kt = g * 4 + q;
            #pragma unroll
            for (int u = 0; u < 2; ++u) {
                const int lhi = h * 2 + u;
                const int k0 = kt * 64 + lhi * 8;
                float4 a0 = *(const float4*)(frow + k0);
                float4 a1 = *(const float4*)(frow + k0 + 4);
                float4 a2 = *(const float4*)(frow + k0 + 32);
                float4 a3 = *(const float4*)(frow + k0 + 36);
                float4 c0 = *(const float4*)(crow + k0);
                float4 c1 = *(const float4*)(crow + k0 + 4);
                float4 c2 = *(const float4*)(crow + k0 + 32);
                float4 c3 = *(const float4*)(crow + k0 + 36);
                float d0 = a0.x-c0.x, d1 = a0.y-c0.y, d2 = a0.z-c0.z, d3 = a0.w-c0.w;
                float d4 = a1.x-c1.x, d5 = a1.y-c1.y, d6 = a1.z-c1.z, d7 = a1.w-c1.w;
                facc += d0*d0 + d1*d1 + d2*d2 + d3*d3 + d4*d4 + d5*d5 + d6*d6 + d7*d7;
                d0 = a2.x-c2.x; d1 = a2.y-c2.y; d2 = a2.z-c2.z; d3 = a2.w-c2.w;
                d4 = a3.x-c3.x; d5 = a3.y-c3.y; d6 = a3.z-c3.z; d7 = a3.w-c3.w;
                facc += d0*d0 + d1*d1 + d2*d2 + d3*d3 + d4*d4 + d5*d5 + d6*d6 + d7*d7;
                uint4 o = { pk4(SCALE_F*a0.x, SCALE_F*a0.y, SCALE_F*a0.z, SCALE_F*a0.w),
                            pk4(SCALE_F*a1.x, SCALE_F*a1.y, SCALE_F*a1.z, SCALE_F*a1.w),
                            pk4(SCALE_F*a2.x, SCALE_F*a2.y, SCALE_F*a2.z, SCALE_F*a2.w),
                            pk4(SCALE_F*a3.x, SCALE_F*a3.y, SCALE_F*a3.z, SCALE_F*a3.w) };
                *(uint4*)(pan + kt * 16384 + lhi * 256) = o;
            }
        }
        for (int d = 32; d >= 1; d >>= 1) facc += __shfl_xor(facc, d);
        __shared__ float redw[4];
        const int wid = tid >> 6, lane = tid & 63;
        if (lane == 0) redw[wid] = facc;
        __syncthreads();
        if (tid == 0) fisher_part[blockIdx.x] = redw[0] + redw[1] + redw[2] + redw[3];
    } else {
        const int b = blockIdx.x - 512;
        const int ct = b >> 3, ktg = b & 7;
        const int rcol = tid >> 1, h = tid & 1;
        const int gc = ct * 128 + rcol;
        char* pan = B_pre + (size_t)ct * PANEL_BB + (rcol >> 4) * 1024 + (rcol & 15) * 16;
        #pragma unroll
        for (int q = 0; q < 2; ++q) {
            const int kt = ktg * 2 + q;
            #pragma unroll
            for (int u = 0; u < 2; ++u) {
                const int lhi = h * 2 + u;
                uint4 o;
                if (gc < C_CLS) {
                    const float* src = W + (size_t)gc * F_DIM + kt * 64 + lhi * 8;
                    float4 a0 = *(const float4*)(src);
                    float4 a1 = *(const float4*)(src + 4);
                    float4 a2 = *(const float4*)(src + 32);
                    float4 a3 = *(const float4*)(src + 36);
                    o = (uint4){ pk4(SCALE_W*a0.x, SCALE_W*a0.y, SCALE_W*a0.z, SCALE_W*a0.w),
                                 pk4(SCALE_W*a1.x, SCALE_W*a1.y, SCALE_W*a1.z, SCALE_W*a1.w),
                                 pk4(SCALE_W*a2.x, SCALE_W*a2.y, SCALE_W*a2.z, SCALE_W*a2.w),
                                 pk4(SCALE_W*a3.x, SCALE_W*a3.y, SCALE_W*a3.z, SCALE_W*a3.w) };
                } else {
                    o = (uint4){0u, 0u, 0u, 0u};
                }
                *(uint4*)(pan + kt * 8192 + lhi * 256) = o;
            }
        }
        if (b < C_PAD / 256) {
            const int i = b * 256 + tid;
            bias_pad[i] = (i < C_CLS) ? bias[i] : -1e30f;
        }
    }
}

// ---- 256x128 fp8 flat-MFMA GEMM: A global->reg; B via 8-buffer LDS ring,
// ---- one vmcnt(4)+barrier per 4-K-tile group ----
__global__ __launch_bounds__(256, 2)
void gemm_kernel(const int* __restrict__ labels, const float* __restrict__ biasp,
                 const char* __restrict__ A_pre, const char* __restrict__ B_pre,
                 float* __restrict__ s_part, float* __restrict__ tl_part)
{
    __shared__ alignas(128) char smem[65536];       // 8 x 8KB B-tile ring

    const int cpx = gridDim.x >> 3;                 // XCD swizzle: same-XCD blocks share rb
    const int wg = (blockIdx.x & 7) * cpx + (blockIdx.x >> 3);
    const int cb = wg & 15;
    const int rb = wg >> 4;

    const int tid = threadIdx.x;
    const int w = tid >> 6, lane = tid & 63;
    const int l15 = lane & 15, lhi = lane >> 4;

    const char* Apan = A_pre + (size_t)rb * PANEL_A + w * 4096 + lane * 16;
    const char* Bsrc = B_pre + (size_t)cb * PANEL_BB;

    f32x4 acc[4][8];
    #pragma unroll
    for (int mi = 0; mi < 4; ++mi)
        #pragma unroll
        for (int ni = 0; ni < 8; ++ni) acc[mi][ni] = (f32x4){0.f, 0.f, 0.f, 0.f};

    i64x2 aE[4], aO[4], bE[8], bO[8];

#define LOADA(SA, KTT) do {                                                           \
    const char* pa_ = Apan + (KTT) * 16384;                                           \
    _Pragma("unroll")                                                                 \
    for (int i_ = 0; i_ < 4; ++i_) SA[i_] = *(const i64x2*)(pa_ + i_ * 1024);         \
} while (0)

#define STAGEB(KTT) do {                                                              \
    const char* sb_ = Bsrc + (size_t)(KTT) * 8192 + w * 2048 + lane * 16;             \
    char* db_ = smem + ((KTT) & 7) * 8192 + w * 2048;                                 \
    gl_lds16(sb_, db_);                                                               \
    gl_lds16(sb_ + 1024, db_ + 1024);                                                 \
} while (0)

#define READB(SB, KTT) do {                                                           \
    const char* lb_ = smem + ((KTT) & 7) * 8192 + lane * 16;                          \
    _Pragma("unroll")                                                                 \
    for (int i_ = 0; i_ < 8; ++i_) SB[i_] = *(const i64x2*)(lb_ + i_ * 1024);         \
} while (0)

#define MFMA64(SA, SB) do {                                                           \
    __builtin_amdgcn_s_setprio(1);                                                    \
    _Pragma("unroll")                                                                 \
    for (int kf_ = 0; kf_ < 2; ++kf_)                                                 \
        _Pragma("unroll")                                                             \
        for (int mi_ = 0; mi_ < 4; ++mi_)                                             \
            _Pragma("unroll")                                                         \
            for (int ni_ = 0; ni_ < 8; ++ni_)                                         \
                acc[mi_][ni_] = __builtin_amdgcn_mfma_f32_16x16x32_fp8_fp8(           \
                    SA[mi_][kf_], SB[ni_][kf_], acc[mi_][ni_], 0, 0, 0);              \
    __builtin_amdgcn_s_setprio(0);                                                    \
} while (0)

#define FENCE __builtin_amdgcn_sched_barrier(0)
#define WAITV(N) asm volatile("s_waitcnt vmcnt(" #N ")" ::: "memory")
#define BAR __builtin_amdgcn_s_barrier()

    // prologue: stage B0..B3 (group 0), load A0; gate stages only (A stays in flight)
    STAGEB(0); STAGEB(1); STAGEB(2); STAGEB(3);
    LOADA(aE, 0);
    WAITV(4);            // 8 stage ops done; A0 (4) still in flight
    FENCE; BAR; FENCE;
    READB(bE, 0);
    FENCE;

    #pragma unroll 1
    for (int g = 0; g < 4; ++g) {
        const int k0 = g * 4;
        const bool st = (g < 3);
        // kt = k0
        if (st) STAGEB(k0 + 4);
        LOADA(aO, k0 + 1);
        READB(bO, k0 + 1);
        FENCE;
        MFMA64(aE, bE);
        FENCE;
        // kt = k0+1
        if (st) STAGEB(k0 + 5);
        LOADA(aE, k0 + 2);
        READB(bE, k0 + 2);
        FENCE;
        MFMA64(aO, bO);
        FENCE;
        // kt = k0+2
        if (st) STAGEB(k0 + 6);
        LOADA(aO, k0 + 3);
        READB(bO, k0 + 3);
        FENCE;
        MFMA64(aE, bE);
        FENCE;
        // kt = k0+3: stage last next-group tile, prefetch next-group A, then boundary
        if (st) {
            STAGEB(k0 + 7);
            LOADA(aE, k0 + 4);
        }
        FENCE;
        MFMA64(aO, bO);
        FENCE;
        if (st) {
            WAITV(4);    // all next-group stages done; A(k0+4) may remain in flight
            FENCE; BAR; FENCE;
            READB(bE, k0 + 4);
            FENCE;
        }
    }

#undef LOADA
#undef STAGEB
#undef READB
#undef MFMA64
#undef FENCE
#undef WAITV
#undef BAR

    // epilogue: each wave owns full 128-col rows -> no cross-wave reduce
    float bb[8];
    #pragma unroll
    for (int ni = 0; ni < 8; ++ni)
        bb[ni] = biasp[cb * 128 + ni * 16 + l15];

    #pragma unroll
    for (int mi = 0; mi < 4; ++mi) {
        #pragma unroll
        for (int j = 0; j < 4; ++j) {
            const int rl = w * 64 + mi * 16 + lhi * 4 + j;
            const int lab = labels[rb * 256 + rl];
            float sv = 0.f, tv = 0.f;
            #pragma unroll
            for (int ni = 0; ni < 8; ++ni) {
                const float v = fmaf(acc[mi][ni][j], INV_SCALE, bb[ni]);
                sv += __expf(v);
                const int gc = cb * 128 + ni * 16 + l15;
                tv = (gc == lab) ? v : tv;
            }
            #pragma unroll
            for (int d = 1; d < 16; d <<= 1) {
                sv += __shfl_xor(sv, d);
                tv += __shfl_xor(tv, d);
            }
            if (l15 == 0) {
                const int grow = rb * 256 + rl;
                s_part[(size_t)cb * B_ROWS + grow]  = sv;
                tl_part[(size_t)cb * B_ROWS + grow] = tv;
            }
        }
    }
}

// ---- combine partials across the 16 column panels, per-row aux loss ----
__global__ __launch_bounds__(256)
void rowcomb_kernel(const float* __restrict__ s_part, const float* __restrict__ tl_part,
                    float* __restrict__ aux_part)
{
    const int row = blockIdx.x * 256 + threadIdx.x;
    float s = 0.f, t = 0.f;
    #pragma unroll
    for (int p = 0; p < NCBP; ++p) {
        s += s_part[(size_t)p * B_ROWS + row];
        t += tl_part[(size_t)p * B_ROWS + row];
    }
    float acc = __logf(s) - t;
    for (int d = 32; d >= 1; d >>= 1) acc += __shfl_xor(acc, d);
    __shared__ float red[4];
    const int wid = threadIdx.x >> 6, lane = threadIdx.x & 63;
    if (lane == 0) red[wid] = acc;
    __syncthreads();
    if (threadIdx.x == 0) aux_part[blockIdx.x] = red[0] + red[1] + red[2] + red[3];
}

__global__ __launch_bounds__(256)
void final_kernel(const float* __restrict__ fisher_part, const float* __restrict__ aux_part,
                  float* __restrict__ out)
{
    const int tid = threadIdx.x;
    float acc = fisher_part[tid] + fisher_part[256 + tid];
    if (tid < 64) acc += aux_part[tid];
    for (int d = 32; d >= 1; d >>= 1) acc += __shfl_xor(acc, d);
    __shared__ float red[4];
    const int wid = tid >> 6, lane = tid & 63;
    if (lane == 0) red[wid] = acc;
    __syncthreads();
    if (tid == 0) out[0] = (red[0] + red[1] + red[2] + red[3]) * (1.0f / (float)B_ROWS);
}

extern "C" void kernel_launch(void* const* d_in, const int* in_sizes, int n_in,
                              void* d_out, int out_size, void* d_ws, size_t ws_size,
                              hipStream_t stream)
{
    (void)in_sizes; (void)n_in; (void)out_size; (void)ws_size;
    const float* feat    = (const float*)d_in[0];
    const int*   labels  = (const int*)  d_in[1];
    const float* centers = (const float*)d_in[2];
    const float* W       = (const float*)d_in[3];
    const float* bias    = (const float*)d_in[4];
    float* out = (float*)d_out;
    char* ws = (char*)d_ws;

    const size_t szA    = (size_t)NRB  * PANEL_A;   // 16,777,216
    const size_t szB    = (size_t)NCBP * PANEL_BB;  //  2,097,152
    const size_t szBias = (size_t)C_PAD * 4;

    char* A_pre = ws;
    char* B_pre = ws + szA;
    float* bias_pad    = (float*)(ws + szA + szB);
    float* s_part      = (float*)(ws + szA + szB + szBias);
    float* tl_part     = s_part + (size_t)NCBP * B_ROWS;
    float* fisher_part = tl_part + (size_t)NCBP * B_ROWS;
    float* aux_part    = fisher_part + 512;

    prep_kernel<<<640, 256, 0, stream>>>(feat, labels, centers, W, bias,
                                         A_pre, B_pre, bias_pad, fisher_part);
    gemm_kernel<<<NRB * NCBP, 256, 0, stream>>>(labels, bias_pad, A_pre, B_pre, s_part, tl_part);
    rowcomb_kernel<<<B_ROWS / 256, 256, 0, stream>>>(s_part, tl_part, aux_part);
    final_kernel<<<1, 256, 0, stream>>>(fisher_part, aux_part, out);
}

// Round 14
// 84.449 us; speedup vs baseline: 2.1793x; 2.1793x over previous
//
#include <hip/hip_runtime.h>
#include <stdint.h>

#define B_ROWS 16384
#define C_CLS  2000
#define C_PAD  2048
#define F_DIM  1024
#define KT     16                         // K-tiles of 64
#define NRB    64                         // gemm row blocks (256 rows)
#define NCBP   16                         // gemm col panels (128 cols)
#define PANEL_A 262144                    // 16 kt x 16 frags x 1024 B
#define PANEL_BB 131072                   // 16 kt x 8 frags x 1024 B

typedef float f32x4 __attribute__((ext_vector_type(4)));
typedef long long i64x2 __attribute__((ext_vector_type(2)));

#define SCALE_F 4.0f
#define SCALE_W 16.0f
#define INV_SCALE 0.015625f               // 1/64

__device__ __forceinline__ void gl_lds16(const void* g, void* l) {
    __builtin_amdgcn_global_load_lds(
        (const __attribute__((address_space(1))) unsigned int*)g,
        (__attribute__((address_space(3))) unsigned int*)l, 16, 0, 0);
}

__device__ __forceinline__ unsigned int pk4(float a, float b, float c, float d) {
    int u = __builtin_amdgcn_cvt_pk_fp8_f32(a, b, 0, false);   // bytes 0,1
    u = __builtin_amdgcn_cvt_pk_fp8_f32(c, d, u, true);        // bytes 2,3
    return (unsigned int)u;
}

// Fragment-linear panels: frag f covers rows f*16..+16; lane l at byte l*16 of the
// 1024B frag; 16B = k[lhi*8..+8) ∪ [32+lhi*8..+8) (i64x2 = [kf0,kf1]) — R10/R11-verified.

// ---- fused prepass: blocks 0..511 = A (feat->fp8 + fisher), 512..639 = B (W->fp8 + bias) ----
__global__ __launch_bounds__(256)
void prep_kernel(const float* __restrict__ feat, const int* __restrict__ labels,
                 const float* __restrict__ centers, const float* __restrict__ W,
                 const float* __restrict__ bias,
                 char* __restrict__ A_pre, char* __restrict__ B_pre,
                 float* __restrict__ bias_pad, float* __restrict__ fisher_part)
{
    const int tid = threadIdx.x;
    if (blockIdx.x < 512) {
        const int rt = blockIdx.x >> 2, g = blockIdx.x & 3;   // rt: 128-row half-panels
        const int rb = rt >> 1;
        const int r = tid >> 1, h = tid & 1;
        const int grow = rt * 128 + r;
        const int lab = labels[grow];
        const float* frow = feat    + (size_t)grow * F_DIM;
        const float* crow = centers + (size_t)lab  * F_DIM;
        const int frag = (rt & 1) * 8 + (r >> 4);
        char* pan = A_pre + (size_t)rb * PANEL_A + frag * 1024 + (r & 15) * 16;
        float facc = 0.f;
        #pragma unroll
        for (int q = 0; q < 4; ++q) {
            const int kt = g * 4 + q;
            #pragma unroll
            for (int u = 0; u < 2; ++u) {
                const int lhi = h * 2 + u;
                const int k0 = kt * 64 + lhi * 8;
                float4 a0 = *(const float4*)(frow + k0);
                float4 a1 = *(const float4*)(frow + k0 + 4);
                float4 a2 = *(const float4*)(frow + k0 + 32);
                float4 a3 = *(const float4*)(frow + k0 + 36);
                float4 c0 = *(const float4*)(crow + k0);
                float4 c1 = *(const float4*)(crow + k0 + 4);
                float4 c2 = *(const float4*)(crow + k0 + 32);
                float4 c3 = *(const float4*)(crow + k0 + 36);
                float d0 = a0.x-c0.x, d1 = a0.y-c0.y, d2 = a0.z-c0.z, d3 = a0.w-c0.w;
                float d4 = a1.x-c1.x, d5 = a1.y-c1.y, d6 = a1.z-c1.z, d7 = a1.w-c1.w;
                facc += d0*d0 + d1*d1 + d2*d2 + d3*d3 + d4*d4 + d5*d5 + d6*d6 + d7*d7;
                d0 = a2.x-c2.x; d1 = a2.y-c2.y; d2 = a2.z-c2.z; d3 = a2.w-c2.w;
                d4 = a3.x-c3.x; d5 = a3.y-c3.y; d6 = a3.z-c3.z; d7 = a3.w-c3.w;
                facc += d0*d0 + d1*d1 + d2*d2 + d3*d3 + d4*d4 + d5*d5 + d6*d6 + d7*d7;
                uint4 o = { pk4(SCALE_F*a0.x, SCALE_F*a0.y, SCALE_F*a0.z, SCALE_F*a0.w),
                            pk4(SCALE_F*a1.x, SCALE_F*a1.y, SCALE_F*a1.z, SCALE_F*a1.w),
                            pk4(SCALE_F*a2.x, SCALE_F*a2.y, SCALE_F*a2.z, SCALE_F*a2.w),
                            pk4(SCALE_F*a3.x, SCALE_F*a3.y, SCALE_F*a3.z, SCALE_F*a3.w) };
                *(uint4*)(pan + kt * 16384 + lhi * 256) = o;
            }
        }
        for (int d = 32; d >= 1; d >>= 1) facc += __shfl_xor(facc, d);
        __shared__ float redw[4];
        const int wid = tid >> 6, lane = tid & 63;
        if (lane == 0) redw[wid] = facc;
        __syncthreads();
        if (tid == 0) fisher_part[blockIdx.x] = redw[0] + redw[1] + redw[2] + redw[3];
    } else {
        const int b = blockIdx.x - 512;
        const int ct = b >> 3, ktg = b & 7;
        const int rcol = tid >> 1, h = tid & 1;
        const int gc = ct * 128 + rcol;
        char* pan = B_pre + (size_t)ct * PANEL_BB + (rcol >> 4) * 1024 + (rcol & 15) * 16;
        #pragma unroll
        for (int q = 0; q < 2; ++q) {
            const int kt = ktg * 2 + q;
            #pragma unroll
            for (int u = 0; u < 2; ++u) {
                const int lhi = h * 2 + u;
                uint4 o;
                if (gc < C_CLS) {
                    const float* src = W + (size_t)gc * F_DIM + kt * 64 + lhi * 8;
                    float4 a0 = *(const float4*)(src);
                    float4 a1 = *(const float4*)(src + 4);
                    float4 a2 = *(const float4*)(src + 32);
                    float4 a3 = *(const float4*)(src + 36);
                    o = (uint4){ pk4(SCALE_W*a0.x, SCALE_W*a0.y, SCALE_W*a0.z, SCALE_W*a0.w),
                                 pk4(SCALE_W*a1.x, SCALE_W*a1.y, SCALE_W*a1.z, SCALE_W*a1.w),
                                 pk4(SCALE_W*a2.x, SCALE_W*a2.y, SCALE_W*a2.z, SCALE_W*a2.w),
                                 pk4(SCALE_W*a3.x, SCALE_W*a3.y, SCALE_W*a3.z, SCALE_W*a3.w) };
                } else {
                    o = (uint4){0u, 0u, 0u, 0u};
                }
                *(uint4*)(pan + kt * 8192 + lhi * 256) = o;
            }
        }
        if (b < C_PAD / 256) {
            const int i = b * 256 + tid;
            bias_pad[i] = (i < C_CLS) ? bias[i] : -1e30f;
        }
    }
}

// ---- 256x128 fp8 flat-MFMA GEMM: A global->reg; B via 8-buf LDS ring,
// ---- single B reg-set (read just-in-time), one vmcnt(16)+barrier per 4 K-tiles ----
__global__ __launch_bounds__(256, 2)
void gemm_kernel(const int* __restrict__ labels, const float* __restrict__ biasp,
                 const char* __restrict__ A_pre, const char* __restrict__ B_pre,
                 float* __restrict__ s_part, float* __restrict__ tl_part)
{
    __shared__ alignas(128) char smem[65536];       // 8 x 8KB B-tile ring

    const int cpx = gridDim.x >> 3;                 // XCD swizzle: same-XCD blocks share rb
    const int wg = (blockIdx.x & 7) * cpx + (blockIdx.x >> 3);
    const int cb = wg & 15;
    const int rb = wg >> 4;

    const int tid = threadIdx.x;
    const int w = tid >> 6, lane = tid & 63;
    const int l15 = lane & 15, lhi = lane >> 4;

    const char* Apan = A_pre + (size_t)rb * PANEL_A + w * 4096 + lane * 16;
    const char* Bsrc = B_pre + (size_t)cb * PANEL_BB;

    f32x4 acc[4][8];
    #pragma unroll
    for (int mi = 0; mi < 4; ++mi)
        #pragma unroll
        for (int ni = 0; ni < 8; ++ni) acc[mi][ni] = (f32x4){0.f, 0.f, 0.f, 0.f};

    i64x2 aE[4], aO[4], bv[8];                      // single B set: short live range

#define LOADA(SA, KTT) do {                                                           \
    const char* pa_ = Apan + (KTT) * 16384;                                           \
    _Pragma("unroll")                                                                 \
    for (int i_ = 0; i_ < 4; ++i_) SA[i_] = *(const i64x2*)(pa_ + i_ * 1024);         \
} while (0)

#define STAGEB(KTT) do {                                                              \
    const char* sb_ = Bsrc + (size_t)(KTT) * 8192 + w * 2048 + lane * 16;             \
    char* db_ = smem + ((KTT) & 7) * 8192 + w * 2048;                                 \
    gl_lds16(sb_, db_);                                                               \
    gl_lds16(sb_ + 1024, db_ + 1024);                                                 \
} while (0)

#define READB(KTT) do {                                                               \
    const char* lb_ = smem + ((KTT) & 7) * 8192 + lane * 16;                          \
    _Pragma("unroll")                                                                 \
    for (int i_ = 0; i_ < 8; ++i_) bv[i_] = *(const i64x2*)(lb_ + i_ * 1024);         \
} while (0)

#define MFMA64(SA) do {                                                               \
    __builtin_amdgcn_s_setprio(1);                                                    \
    _Pragma("unroll")                                                                 \
    for (int kf_ = 0; kf_ < 2; ++kf_)                                                 \
        _Pragma("unroll")                                                             \
        for (int mi_ = 0; mi_ < 4; ++mi_)                                             \
            _Pragma("unroll")                                                         \
            for (int ni_ = 0; ni_ < 8; ++ni_)                                         \
                acc[mi_][ni_] = __builtin_amdgcn_mfma_f32_16x16x32_fp8_fp8(           \
                    SA[mi_][kf_], bv[ni_][kf_], acc[mi_][ni_], 0, 0, 0);              \
    __builtin_amdgcn_s_setprio(0);                                                    \
} while (0)

#define FENCE __builtin_amdgcn_sched_barrier(0)
#define WAITV(N) asm volatile("s_waitcnt vmcnt(" #N ")" ::: "memory")
#define BAR __builtin_amdgcn_s_barrier()

    // prologue: stage group 0 (tiles 0-3 -> bufs 0-3); load A0; gate stages; barrier
    STAGEB(0); STAGEB(1); STAGEB(2); STAGEB(3);
    LOADA(aE, 0);
    FENCE;
    WAITV(4);            // 8 stage ops done; A0 (4 loads) stays in flight
    FENCE; BAR; FENCE;

    #pragma unroll 1
    for (int g = 0; g < 4; ++g) {
        const int k0 = g * 4;
        const bool st = (g < 3);
        if (st) { STAGEB(k0 + 4); STAGEB(k0 + 5); STAGEB(k0 + 6); STAGEB(k0 + 7); }
        FENCE;
        // t = k0 (aE current)
        READB(k0);
        LOADA(aO, k0 + 1);
        FENCE;
        MFMA64(aE);
        FENCE;
        // t = k0+1
        READB(k0 + 1);
        LOADA(aE, k0 + 2);
        FENCE;
        MFMA64(aO);
        FENCE;
        // t = k0+2
        READB(k0 + 2);
        LOADA(aO, k0 + 3);
        FENCE;
        MFMA64(aE);
        FENCE;
        // t = k0+3
        READB(k0 + 3);
        if (st) LOADA(aE, k0 + 4);
        FENCE;
        MFMA64(aO);
        FENCE;
        if (st) {
            WAITV(16);   // oldest in flight = this group's 8 stage ops -> force done
            FENCE; BAR; FENCE;
        }
    }

#undef LOADA
#undef STAGEB
#undef READB
#undef MFMA64
#undef FENCE
#undef WAITV
#undef BAR

    // epilogue: each wave owns full 128-col rows -> no cross-wave reduce
    float bb[8];
    #pragma unroll
    for (int ni = 0; ni < 8; ++ni)
        bb[ni] = biasp[cb * 128 + ni * 16 + l15];

    #pragma unroll
    for (int mi = 0; mi < 4; ++mi) {
        #pragma unroll
        for (int j = 0; j < 4; ++j) {
            const int rl = w * 64 + mi * 16 + lhi * 4 + j;
            const int lab = labels[rb * 256 + rl];
            float sv = 0.f, tv = 0.f;
            #pragma unroll
            for (int ni = 0; ni < 8; ++ni) {
                const float v = fmaf(acc[mi][ni][j], INV_SCALE, bb[ni]);
                sv += __expf(v);
                const int gc = cb * 128 + ni * 16 + l15;
                tv = (gc == lab) ? v : tv;
            }
            #pragma unroll
            for (int d = 1; d < 16; d <<= 1) {
                sv += __shfl_xor(sv, d);
                tv += __shfl_xor(tv, d);
            }
            if (l15 == 0) {
                const int grow = rb * 256 + rl;
                s_part[(size_t)cb * B_ROWS + grow]  = sv;
                tl_part[(size_t)cb * B_ROWS + grow] = tv;
            }
        }
    }
}

// ---- combine partials across the 16 column panels, per-row aux loss ----
__global__ __launch_bounds__(256)
void rowcomb_kernel(const float* __restrict__ s_part, const float* __restrict__ tl_part,
                    float* __restrict__ aux_part)
{
    const int row = blockIdx.x * 256 + threadIdx.x;
    float s = 0.f, t = 0.f;
    #pragma unroll
    for (int p = 0; p < NCBP; ++p) {
        s += s_part[(size_t)p * B_ROWS + row];
        t += tl_part[(size_t)p * B_ROWS + row];
    }
    float acc = __logf(s) - t;
    for (int d = 32; d >= 1; d >>= 1) acc += __shfl_xor(acc, d);
    __shared__ float red[4];
    const int wid = threadIdx.x >> 6, lane = threadIdx.x & 63;
    if (lane == 0) red[wid] = acc;
    __syncthreads();
    if (threadIdx.x == 0) aux_part[blockIdx.x] = red[0] + red[1] + red[2] + red[3];
}

__global__ __launch_bounds__(256)
void final_kernel(const float* __restrict__ fisher_part, const float* __restrict__ aux_part,
                  float* __restrict__ out)
{
    const int tid = threadIdx.x;
    float acc = fisher_part[tid] + fisher_part[256 + tid];
    if (tid < 64) acc += aux_part[tid];
    for (int d = 32; d >= 1; d >>= 1) acc += __shfl_xor(acc, d);
    __shared__ float red[4];
    const int wid = tid >> 6, lane = tid & 63;
    if (lane == 0) red[wid] = acc;
    __syncthreads();
    if (tid == 0) out[0] = (red[0] + red[1] + red[2] + red[3]) * (1.0f / (float)B_ROWS);
}

extern "C" void kernel_launch(void* const* d_in, const int* in_sizes, int n_in,
                              void* d_out, int out_size, void* d_ws, size_t ws_size,
                              hipStream_t stream)
{
    (void)in_sizes; (void)n_in; (void)out_size; (void)ws_size;
    const float* feat    = (const float*)d_in[0];
    const int*   labels  = (const int*)  d_in[1];
    const float* centers = (const float*)d_in[2];
    const float* W       = (const float*)d_in[3];
    const float* bias    = (const float*)d_in[4];
    float* out = (float*)d_out;
    char* ws = (char*)d_ws;

    const size_t szA    = (size_t)NRB  * PANEL_A;   // 16,777,216
    const size_t szB    = (size_t)NCBP * PANEL_BB;  //  2,097,152
    const size_t szBias = (size_t)C_PAD * 4;

    char* A_pre = ws;
    char* B_pre = ws + szA;
    float* bias_pad    = (float*)(ws + szA + szB);
    float* s_part      = (float*)(ws + szA + szB + szBias);
    float* tl_part     = s_part + (size_t)NCBP * B_ROWS;
    float* fisher_part = tl_part + (size_t)NCBP * B_ROWS;
    float* aux_part    = fisher_part + 512;

    prep_kernel<<<640, 256, 0, stream>>>(feat, labels, centers, W, bias,
                                         A_pre, B_pre, bias_pad, fisher_part);
    gemm_kernel<<<NRB * NCBP, 256, 0, stream>>>(labels, bias_pad, A_pre, B_pre, s_part, tl_part);
    rowcomb_kernel<<<B_ROWS / 256, 256, 0, stream>>>(s_part, tl_part, aux_part);
    final_kernel<<<1, 256, 0, stream>>>(fisher_part, aux_part, out);
}